// Round 21
// baseline (68.013 us; speedup 1.0000x reference)
//
#include <hip/hip_runtime.h>

#define NN 100000
#define NE 1250000
#define HD 64
#define BMW 3125             // node-bitmap words = NN/32
#define EBW 39063            // edge-bitmap words = ceil(NE/32)
#define NE4 312500           // NE/4 int4 units

#define MBLK 256             // 1 block/CU: comfortably co-resident (R20's 512
                             // sat on the VGPR cliff -> blocks not scheduled ->
                             // barrier guard-escape -> wrong output)
#define MTPB 512
#define MNTH (MBLK * MTPB)   // 131072 threads
#define MWAVES (MNTH / 64)   // 2048 waves
#define NILP 3               // ceil(NE4 / MNTH)

// 2-node graph: memset + mega-kernel. Barrier protocol (R19-proven):
//  - arrivals: fetch_add on 16 spread slots (RMW -> coherence point)
//  - master (block 0) polls arrivals with plain relaxed loads (fresh: the
//    arrival RMWs invalidate sharers), releases via fetch_add on 16
//    replicated lines (plain-store release can sit dirty in an XCD-L2 ->
//    R17's 35ms stall)
//  - waiters poll ONLY their own replica with plain loads.
// vs R19: scatter phases E/G use wave-strided word mapping (w2 = gw;
// w2 += MWAVES) with lane-broadcast words — hit edges spread ~2/wave instead
// of ~6 serial on the first 611 waves. Static mapping => replay-deterministic
// (same class as R14-R19, absmax 0 throughout).

__device__ __forceinline__ unsigned ldg_u(const unsigned* p) {
    return __hip_atomic_load(p, __ATOMIC_RELAXED, __HIP_MEMORY_SCOPE_AGENT);
}
__device__ __forceinline__ int ldg_i(const int* p) {
    return __hip_atomic_load(p, __ATOMIC_RELAXED, __HIP_MEMORY_SCOPE_AGENT);
}
__device__ __forceinline__ float ldg_f(const float* p) {
    return __hip_atomic_load(p, __ATOMIC_RELAXED, __HIP_MEMORY_SCOPE_AGENT);
}
__device__ __forceinline__ void stg_f(float* p, float v) {
    __hip_atomic_store(p, v, __ATOMIC_RELAXED, __HIP_MEMORY_SCOPE_AGENT);
}

__device__ __forceinline__ void gbar(unsigned* cnt16, unsigned* rel16,
                                     unsigned target, unsigned phase) {
    __syncthreads();     // drains vmcnt: block's stores/atomics reached LLC
    if (threadIdx.x == 0) {
        __hip_atomic_fetch_add(&cnt16[(blockIdx.x & 15u) * 16], 1u,
                               __ATOMIC_RELAXED, __HIP_MEMORY_SCOPE_AGENT);
        long guard = 0;
        if (blockIdx.x == 0) {
            for (;;) {                           // sole arrival poller
                unsigned s = 0;
#pragma unroll
                for (int i = 0; i < 16; ++i)
                    s += __hip_atomic_load(&cnt16[i * 16], __ATOMIC_RELAXED,
                                           __HIP_MEMORY_SCOPE_AGENT);
                if (s >= target) break;
                __builtin_amdgcn_s_sleep(1);
                if (++guard > (1L << 22)) break;   // deadlock escape
            }
#pragma unroll
            for (int i = 0; i < 16; ++i)           // release: RMW (fresh+inval)
                __hip_atomic_fetch_add(&rel16[i * 16], 1u,
                                       __ATOMIC_RELAXED, __HIP_MEMORY_SCOPE_AGENT);
        } else {
            const unsigned slot = (blockIdx.x & 15u) * 16;
            for (;;) {                           // poll own replica only
                if (__hip_atomic_load(&rel16[slot], __ATOMIC_RELAXED,
                                      __HIP_MEMORY_SCOPE_AGENT) >= phase) break;
                __builtin_amdgcn_s_sleep(1);
                if (++guard > (1L << 22)) break;
            }
        }
        asm volatile("" ::: "memory");
    }
    __syncthreads();
}

__device__ __forceinline__ int cmp4(int4 v, int k) {
    return (k == 0) ? v.x : (k == 1) ? v.y : (k == 2) ? v.z : v.w;
}

__global__ __launch_bounds__(MTPB, 1) void k_main(
        const int* __restrict__ z, const int* __restrict__ src,
        const int* __restrict__ dst, const int* __restrict__ pair,
        const float* __restrict__ zt,
        const float* __restrict__ W1, const float* __restrict__ b1,
        const float* __restrict__ W2, const float* __restrict__ b2,
        const float* __restrict__ W3, const float* __restrict__ b3,
        const float* __restrict__ l1w, const float* __restrict__ l1b,
        const float* __restrict__ l2w, const float* __restrict__ l2b,
        float* out, float* bufA, float* bufB, float* x3buf,
        float* cnt_out, float* cnt_in, int* cpair,
        unsigned* B0, unsigned* B1, unsigned* B2,
        unsigned* EB1, unsigned* EB2, unsigned* cnt16, unsigned* rel16) {
    __shared__ unsigned bmA[BMW];    // 12.5 KB
    __shared__ unsigned bmB[BMW];    // 12.5 KB
    __shared__ float arow[8][HD];    // 2 KB wave-private row staging
    __shared__ float xls[2 * HD];
    const int tid = threadIdx.x, blk = blockIdx.x;
    const int gtid = blk * MTPB + tid;
    const int wv = tid >> 6, ln = tid & 63;      // 8 local waves
    const int gw = gtid >> 6;                    // 0..2047 global wave
    const int p0 = pair[0], p1 = pair[1];

    // ---- A: pair-sweep — build B2 + cpair multiplicities, lazy-zero ----
    if (blk == 0 && tid == 0) { stg_f(&cnt_in[p0], 0.f); stg_f(&cnt_in[p1], 0.f); }
    {
        int4 va[NILP];
#pragma unroll
        for (int j = 0; j < NILP; ++j) {
            int t = gtid + j * MNTH;
            va[j] = (t < NE4) ? ((const int4*)dst)[t] : make_int4(-1, -1, -1, -1);
        }
#pragma unroll
        for (int j = 0; j < NILP; ++j) {
            int t = gtid + j * MNTH;
            if (t >= NE4) continue;
#pragma unroll
            for (int k = 0; k < 4; ++k) {
                int d = cmp4(va[j], k);
                if (d == p0 || d == p1) {
                    int s = src[t * 4 + k];
                    atomicAdd(&cpair[s], (d == p0) ? 1 : 0x10000);
                    unsigned m = 1u << (s & 31);
                    unsigned old = atomicOr(&B2[s >> 5], m);
                    if (!(old & m)) { stg_f(&cnt_out[s], 0.f); stg_f(&cnt_in[s], 0.f); }
                }
            }
        }
    }
    gbar(cnt16, rel16, 1u * MBLK, 1u);

    // ---- B: sweep dst∈B2 — build B1 + EB2, lazy-zero ----
    for (int i = tid; i < BMW; i += MTPB) bmA[i] = ldg_u(&B2[i]);
    __syncthreads();
    {
        int4 va[NILP];
#pragma unroll
        for (int j = 0; j < NILP; ++j) {
            int t = gtid + j * MNTH;
            va[j] = (t < NE4) ? ((const int4*)dst)[t] : make_int4(-1, -1, -1, -1);
        }
#pragma unroll
        for (int j = 0; j < NILP; ++j) {
            int t = gtid + j * MNTH;
            if (t >= NE4) continue;
#pragma unroll
            for (int k = 0; k < 4; ++k) {
                int d = cmp4(va[j], k);
                if (d >= 0 && ((bmA[d >> 5] >> (d & 31)) & 1u)) {
                    int e = t * 4 + k, s = src[e];
                    atomicOr(&EB2[e >> 5], 1u << (e & 31));
                    unsigned m = 1u << (s & 31);
                    unsigned old = atomicOr(&B1[s >> 5], m);
                    if (!(old & m)) { stg_f(&cnt_out[s], 0.f); stg_f(&cnt_in[s], 0.f); }
                }
            }
        }
    }
    gbar(cnt16, rel16, 2u * MBLK, 2u);

    // ---- C: seed B0|=B1|B2; zero agg rows; sweep dst∈B1 -> EB1 + B0 marks
    //      + lazy-zero cnt_out; in-deg for dst∈(B1|B2|pair) ----
    for (int i = gtid; i < BMW; i += MNTH) {
        unsigned u = ldg_u(&B1[i]) | ldg_u(&B2[i]);
        if (u) atomicOr(&B0[i], u);
    }
    for (int w2 = gw; w2 < BMW; w2 += MWAVES) {
        unsigned m1 = ldg_u(&B1[w2]);
        while (m1) { int b_ = __ffs(m1) - 1; m1 &= m1 - 1;
                     stg_f(&bufB[(w2 * 32 + b_) * HD + ln], 0.f); }
        unsigned m2 = ldg_u(&B2[w2]);
        while (m2) { int b_ = __ffs(m2) - 1; m2 &= m2 - 1;
                     stg_f(&bufA[(w2 * 32 + b_) * HD + ln], 0.f); }
    }
    for (int i = tid; i < BMW; i += MTPB) {
        unsigned u1 = ldg_u(&B1[i]);
        bmA[i] = u1;
        bmB[i] = u1 | ldg_u(&B2[i]);
    }
    __syncthreads();
    {
        int4 va[NILP];
#pragma unroll
        for (int j = 0; j < NILP; ++j) {
            int t = gtid + j * MNTH;
            va[j] = (t < NE4) ? ((const int4*)dst)[t] : make_int4(-1, -1, -1, -1);
        }
#pragma unroll
        for (int j = 0; j < NILP; ++j) {
            int t = gtid + j * MNTH;
            if (t >= NE4) continue;
#pragma unroll
            for (int k = 0; k < 4; ++k) {
                int d = cmp4(va[j], k);
                if ((bmA[d >> 5] >> (d & 31)) & 1u) {
                    int e = t * 4 + k, s = src[e];
                    atomicOr(&EB1[e >> 5], 1u << (e & 31));
                    unsigned m = 1u << (s & 31);
                    unsigned old = atomicOr(&B0[s >> 5], m);
                    if (!(old & m)) stg_f(&cnt_out[s], 0.f);
                }
                if (((bmB[d >> 5] >> (d & 31)) & 1u) || d == p0 || d == p1)
                    atomicAdd(&cnt_in[d], 1.0f);
            }
        }
    }
    gbar(cnt16, rel16, 3u * MBLK, 3u);

    // ---- D: out-deg sweep over union B0 (src pass) ----
    for (int i = tid; i < BMW; i += MTPB) bmB[i] = ldg_u(&B0[i]);
    __syncthreads();
    {
        int4 va[NILP];
#pragma unroll
        for (int j = 0; j < NILP; ++j) {
            int t = gtid + j * MNTH;
            va[j] = (t < NE4) ? ((const int4*)src)[t] : make_int4(-1, -1, -1, -1);
        }
#pragma unroll
        for (int j = 0; j < NILP; ++j) {
            int t = gtid + j * MNTH;
            if (t >= NE4) continue;
#pragma unroll
            for (int k = 0; k < 4; ++k) {
                int s = cmp4(va[j], k);
                if ((bmB[s >> 5] >> (s & 31)) & 1u) atomicAdd(&cnt_out[s], 1.0f);
            }
        }
    }
    gbar(cnt16, rel16, 4u * MBLK, 4u);

    // ---- E: scatter1 via EB1 (wave-strided words, lane-broadcast) ----
    // agg1[d] += w0(s) * zt[z[s]]; ~2 hit edges per wave at 2048 waves.
    for (int w2 = gw; w2 < EBW; w2 += MWAVES) {
        unsigned wd = ldg_u(&EB1[w2]);     // all 64 lanes: same word (broadcast)
        while (wd) {
            int b_ = __ffs(wd) - 1; wd &= wd - 1;
            int e = w2 * 32 + b_;
            int s = src[e], d = dst[e];
            float w0 = 1.0f / sqrtf(fmaxf(ldg_f(&cnt_out[s]), 1.0f));
            atomicAdd(&bufB[d * HD + ln], w0 * zt[z[s] * HD + ln]);
        }
    }
    gbar(cnt16, rel16, 5u * MBLK, 5u);

    // ---- F: gemm1 over B1 bits — x1 = relu((agg1*nin)@W1+b1) in bufB ----
    for (int w2 = gw; w2 < BMW; w2 += MWAVES) {
        unsigned mk = ldg_u(&B1[w2]);
        while (mk) {
            int b_ = __ffs(mk) - 1; mk &= mk - 1;
            int v = w2 * 32 + b_;
            float nin = 1.0f / sqrtf(fmaxf(ldg_f(&cnt_in[v]), 1.0f));
            arow[wv][ln] = ldg_f(&bufB[v * HD + ln]) * nin;
            float acc = b1[ln];
#pragma unroll
            for (int i = 0; i < HD; ++i)
                acc += arow[wv][i] * W1[i * HD + ln];
            stg_f(&bufB[v * HD + ln], fmaxf(acc, 0.0f));
        }
    }
    gbar(cnt16, rel16, 6u * MBLK, 6u);

    // ---- G: scatter2 via EB2 (wave-strided) — agg2[d] += w0(s) * x1[s] ----
    for (int w2 = gw; w2 < EBW; w2 += MWAVES) {
        unsigned wd = ldg_u(&EB2[w2]);
        while (wd) {
            int b_ = __ffs(wd) - 1; wd &= wd - 1;
            int e = w2 * 32 + b_;
            int s = src[e], d = dst[e];
            float w0 = 1.0f / sqrtf(fmaxf(ldg_f(&cnt_out[s]), 1.0f));
            atomicAdd(&bufA[d * HD + ln], w0 * ldg_f(&bufB[s * HD + ln]));
        }
    }
    gbar(cnt16, rel16, 7u * MBLK, 7u);

    // ---- H: gemm2 over B2 bits + fused scatter3 via cpair multiplicities ----
    for (int w2 = gw; w2 < BMW; w2 += MWAVES) {
        unsigned mk = ldg_u(&B2[w2]);
        while (mk) {
            int b_ = __ffs(mk) - 1; mk &= mk - 1;
            int v = w2 * 32 + b_;
            float nin = 1.0f / sqrtf(fmaxf(ldg_f(&cnt_in[v]), 1.0f));
            arow[wv][ln] = ldg_f(&bufA[v * HD + ln]) * nin;
            float acc = b2[ln];
#pragma unroll
            for (int i = 0; i < HD; ++i)
                acc += arow[wv][i] * W2[i * HD + ln];
            float x2 = fmaxf(acc, 0.0f);
            int cp = ldg_i(&cpair[v]);
            int c0 = cp & 0xffff, c1 = cp >> 16;
            float w0v = 1.0f / sqrtf(fmaxf(ldg_f(&cnt_out[v]), 1.0f));
            if (c0) atomicAdd(&x3buf[ln], (float)c0 * (w0v * x2));
            if (c1) atomicAdd(&x3buf[HD + ln], (float)c1 * (w0v * x2));
        }
    }

    // ---- barrier 8: arrive-and-exit for blocks != 0; block 0 waits ----
    __syncthreads();
    if (tid == 0)
        __hip_atomic_fetch_add(&cnt16[(blk & 15) * 16], 1u,
                               __ATOMIC_RELAXED, __HIP_MEMORY_SCOPE_AGENT);
    if (blk != 0) return;
    if (tid == 0) {
        long guard = 0;
        for (;;) {
            unsigned s = 0;
#pragma unroll
            for (int i = 0; i < 16; ++i)
                s += __hip_atomic_load(&cnt16[i * 16], __ATOMIC_RELAXED,
                                       __HIP_MEMORY_SCOPE_AGENT);
            if (s >= 8u * MBLK) break;
            __builtin_amdgcn_s_sleep(1);
            if (++guard > (1L << 22)) break;
        }
        asm volatile("" ::: "memory");
    }
    __syncthreads();

    // ---- J (block 0): gemm3 (no relu) + final MLP ----
    if (tid < 128) {
        int pv = wv ? p1 : p0;
        int rs = (wv && p1 != p0) ? 1 : 0;       // p0==p1: both use row 0
        float nin = 1.0f / sqrtf(fmaxf(ldg_f(&cnt_in[pv]), 1.0f));
        arow[wv][ln] = ldg_f(&x3buf[rs * HD + ln]) * nin;
        float acc = b3[ln];
#pragma unroll
        for (int i = 0; i < HD; ++i)
            acc += arow[wv][i] * W3[i * HD + ln];
        xls[wv * HD + ln] = acc;
    }
    __syncthreads();
    if (tid < 64) {
        arow[0][tid] = xls[tid] * xls[HD + tid];   // h
        float t2 = l1b[tid];
#pragma unroll
        for (int i = 0; i < HD; ++i)
            t2 += arow[0][i] * l1w[i * HD + tid];
        t2 = fmaxf(t2, 0.0f);
        float val = t2 * l2w[tid];
#pragma unroll
        for (int off = 32; off; off >>= 1)
            val += __shfl_down(val, off, 64);
        if (tid == 0) out[0] = val + l2b[0];
    }
}

extern "C" void kernel_launch(void* const* d_in, const int* in_sizes, int n_in,
                              void* d_out, int out_size, void* d_ws, size_t ws_size,
                              hipStream_t stream) {
    const int*   z    = (const int*)d_in[0];
    const int*   src  = (const int*)d_in[1];
    const int*   dst  = (const int*)d_in[2];
    const int*   pair = (const int*)d_in[3];
    const float* zt   = (const float*)d_in[4];
    const float* W1   = (const float*)d_in[5];
    const float* b1   = (const float*)d_in[6];
    const float* W2   = (const float*)d_in[7];
    const float* b2   = (const float*)d_in[8];
    const float* W3   = (const float*)d_in[9];
    const float* b3   = (const float*)d_in[10];
    const float* l1w  = (const float*)d_in[11];
    const float* l1b  = (const float*)d_in[12];
    const float* l2w  = (const float*)d_in[13];
    const float* l2b  = (const float*)d_in[14];
    float* out = (float*)d_out;

    char* w = (char*)d_ws;
    auto alloc = [&](size_t bytes) {
        char* p = w;
        w += (bytes + 255) & ~(size_t)255;
        return p;
    };
    // contiguous memset region: [cnt16 | rel16 | x3buf | B0 B1 B2 | EB1 EB2 | cpair]
    unsigned* cnt16   = (unsigned*)alloc(1024);
    unsigned* rel16   = (unsigned*)alloc(1024);
    float*    x3buf   = (float*)alloc(2 * HD * 4);
    unsigned* B0      = (unsigned*)alloc((size_t)BMW * 4);
    unsigned* B1      = (unsigned*)alloc((size_t)BMW * 4);
    unsigned* B2      = (unsigned*)alloc((size_t)BMW * 4);
    unsigned* EB1     = (unsigned*)alloc((size_t)EBW * 4);
    unsigned* EB2     = (unsigned*)alloc((size_t)EBW * 4);
    int*      cpair   = (int*)alloc((size_t)NN * 4);
    char*     zend    = w;
    float*    bufA    = (float*)alloc((size_t)NN * HD * 4);
    float*    bufB    = (float*)alloc((size_t)NN * HD * 4);
    float*    cnt_out = (float*)alloc((size_t)NN * 4);
    float*    cnt_in  = (float*)alloc((size_t)NN * 4);

    hipMemsetAsync(cnt16, 0, (size_t)(zend - (char*)cnt16), stream);
    k_main<<<MBLK, MTPB, 0, stream>>>(z, src, dst, pair, zt,
                                      W1, b1, W2, b2, W3, b3,
                                      l1w, l1b, l2w, l2b, out,
                                      bufA, bufB, x3buf, cnt_out, cnt_in,
                                      cpair, B0, B1, B2, EB1, EB2, cnt16, rel16);
}

// Round 22
// 64.264 us; speedup vs baseline: 1.0583x; 1.0583x over previous
//
#include <hip/hip_runtime.h>

#define NN 100000
#define NE 1250000
#define HD 64
#define BMW 3125             // node-bitmap words = NN/32
#define EBW 39063            // edge-bitmap words = ceil(NE/32)
#define NE4 312500           // NE/4 int4 units

#define MBLK 256             // 1 block/CU: comfortably co-resident (512 sat on
                             // the VGPR cliff -> unscheduled blocks -> wrong)
#define MTPB 512
#define MNTH (MBLK * MTPB)   // 131072 threads
#define MWAVES (MNTH / 64)   // 2048 waves
#define NILP 3               // ceil(NE4 / MNTH)

// 2-node graph: memset + mega-kernel. Barrier protocol (R19-proven):
//  - arrivals: fetch_add on 16 spread slots (RMW -> coherence point)
//  - master (block 0) polls arrivals with plain relaxed loads (fresh: the
//    arrival RMWs invalidate sharers), releases via fetch_add on 16
//    replicated lines (plain-store release can sit dirty in an XCD-L2)
//  - waiters poll ONLY their own replica with plain loads.
// vs R19: read-only data is loaded ONCE and carried across barriers in
// registers — dst int4s shared by sweeps A/B/C; src int4s for D prefetched
// before gbar(3); EB1/EB2 scatter words prefetched one barrier early. The
// gbar asm memory-clobber forbids the compiler from doing this itself.
// Scatters: R19's lane-distributed mapping (coalesced EB reads; R21's
// wave-strided variant measured slightly worse).

__device__ __forceinline__ unsigned ldg_u(const unsigned* p) {
    return __hip_atomic_load(p, __ATOMIC_RELAXED, __HIP_MEMORY_SCOPE_AGENT);
}
__device__ __forceinline__ int ldg_i(const int* p) {
    return __hip_atomic_load(p, __ATOMIC_RELAXED, __HIP_MEMORY_SCOPE_AGENT);
}
__device__ __forceinline__ float ldg_f(const float* p) {
    return __hip_atomic_load(p, __ATOMIC_RELAXED, __HIP_MEMORY_SCOPE_AGENT);
}
__device__ __forceinline__ void stg_f(float* p, float v) {
    __hip_atomic_store(p, v, __ATOMIC_RELAXED, __HIP_MEMORY_SCOPE_AGENT);
}

__device__ __forceinline__ void gbar(unsigned* cnt16, unsigned* rel16,
                                     unsigned target, unsigned phase) {
    __syncthreads();     // drains vmcnt: block's stores/atomics reached LLC
    if (threadIdx.x == 0) {
        __hip_atomic_fetch_add(&cnt16[(blockIdx.x & 15u) * 16], 1u,
                               __ATOMIC_RELAXED, __HIP_MEMORY_SCOPE_AGENT);
        long guard = 0;
        if (blockIdx.x == 0) {
            for (;;) {                           // sole arrival poller
                unsigned s = 0;
#pragma unroll
                for (int i = 0; i < 16; ++i)
                    s += __hip_atomic_load(&cnt16[i * 16], __ATOMIC_RELAXED,
                                           __HIP_MEMORY_SCOPE_AGENT);
                if (s >= target) break;
                __builtin_amdgcn_s_sleep(1);
                if (++guard > (1L << 22)) break;   // deadlock escape
            }
#pragma unroll
            for (int i = 0; i < 16; ++i)           // release: RMW (fresh+inval)
                __hip_atomic_fetch_add(&rel16[i * 16], 1u,
                                       __ATOMIC_RELAXED, __HIP_MEMORY_SCOPE_AGENT);
        } else {
            const unsigned slot = (blockIdx.x & 15u) * 16;
            for (;;) {                           // poll own replica only
                if (__hip_atomic_load(&rel16[slot], __ATOMIC_RELAXED,
                                      __HIP_MEMORY_SCOPE_AGENT) >= phase) break;
                __builtin_amdgcn_s_sleep(1);
                if (++guard > (1L << 22)) break;
            }
        }
        asm volatile("" ::: "memory");
    }
    __syncthreads();
}

__device__ __forceinline__ int cmp4(int4 v, int k) {
    return (k == 0) ? v.x : (k == 1) ? v.y : (k == 2) ? v.z : v.w;
}

__global__ __launch_bounds__(MTPB, 1) void k_main(
        const int* __restrict__ z, const int* __restrict__ src,
        const int* __restrict__ dst, const int* __restrict__ pair,
        const float* __restrict__ zt,
        const float* __restrict__ W1, const float* __restrict__ b1,
        const float* __restrict__ W2, const float* __restrict__ b2,
        const float* __restrict__ W3, const float* __restrict__ b3,
        const float* __restrict__ l1w, const float* __restrict__ l1b,
        const float* __restrict__ l2w, const float* __restrict__ l2b,
        float* out, float* bufA, float* bufB, float* x3buf,
        float* cnt_out, float* cnt_in, int* cpair,
        unsigned* B0, unsigned* B1, unsigned* B2,
        unsigned* EB1, unsigned* EB2, unsigned* cnt16, unsigned* rel16) {
    __shared__ unsigned bmA[BMW];    // 12.5 KB
    __shared__ unsigned bmB[BMW];    // 12.5 KB
    __shared__ float arow[8][HD];    // 2 KB wave-private row staging
    __shared__ float xls[2 * HD];
    const int tid = threadIdx.x, blk = blockIdx.x;
    const int gtid = blk * MTPB + tid;
    const int wv = tid >> 6, ln = tid & 63;      // 8 local waves
    const int gw = gtid >> 6;                    // 0..2047 global wave
    const int p0 = pair[0], p1 = pair[1];
    const int ew = gw * 64 + ln;                 // this lane's EB word index

    // ---- load dst int4s ONCE; registers carried through sweeps A, B, C ----
    int4 vd[NILP];
#pragma unroll
    for (int j = 0; j < NILP; ++j) {
        int t = gtid + j * MNTH;
        vd[j] = (t < NE4) ? ((const int4*)dst)[t] : make_int4(-1, -1, -1, -1);
    }

    // ---- A: pair-sweep — build B2 + cpair multiplicities, lazy-zero ----
    if (blk == 0 && tid == 0) { stg_f(&cnt_in[p0], 0.f); stg_f(&cnt_in[p1], 0.f); }
#pragma unroll
    for (int j = 0; j < NILP; ++j) {
        int t = gtid + j * MNTH;
        if (t >= NE4) continue;
#pragma unroll
        for (int k = 0; k < 4; ++k) {
            int d = cmp4(vd[j], k);
            if (d == p0 || d == p1) {
                int s = src[t * 4 + k];
                atomicAdd(&cpair[s], (d == p0) ? 1 : 0x10000);
                unsigned m = 1u << (s & 31);
                unsigned old = atomicOr(&B2[s >> 5], m);
                if (!(old & m)) { stg_f(&cnt_out[s], 0.f); stg_f(&cnt_in[s], 0.f); }
            }
        }
    }
    gbar(cnt16, rel16, 1u * MBLK, 1u);

    // ---- B: sweep dst∈B2 — build B1 + EB2, lazy-zero (reuses vd) ----
    for (int i = tid; i < BMW; i += MTPB) bmA[i] = ldg_u(&B2[i]);
    __syncthreads();
#pragma unroll
    for (int j = 0; j < NILP; ++j) {
        int t = gtid + j * MNTH;
        if (t >= NE4) continue;
#pragma unroll
        for (int k = 0; k < 4; ++k) {
            int d = cmp4(vd[j], k);
            if ((bmA[d >> 5] >> (d & 31)) & 1u) {
                int e = t * 4 + k, s = src[e];
                atomicOr(&EB2[e >> 5], 1u << (e & 31));
                unsigned m = 1u << (s & 31);
                unsigned old = atomicOr(&B1[s >> 5], m);
                if (!(old & m)) { stg_f(&cnt_out[s], 0.f); stg_f(&cnt_in[s], 0.f); }
            }
        }
    }
    gbar(cnt16, rel16, 2u * MBLK, 2u);

    // ---- C: seed B0|=B1|B2; zero agg rows; sweep dst∈B1 -> EB1 + B0 marks
    //      + lazy-zero cnt_out; in-deg for dst∈(B1|B2|pair) (reuses vd) ----
    for (int i = gtid; i < BMW; i += MNTH) {
        unsigned u = ldg_u(&B1[i]) | ldg_u(&B2[i]);
        if (u) atomicOr(&B0[i], u);
    }
    for (int w2 = gw; w2 < BMW; w2 += MWAVES) {
        unsigned m1 = ldg_u(&B1[w2]);
        while (m1) { int b_ = __ffs(m1) - 1; m1 &= m1 - 1;
                     stg_f(&bufB[(w2 * 32 + b_) * HD + ln], 0.f); }
        unsigned m2 = ldg_u(&B2[w2]);
        while (m2) { int b_ = __ffs(m2) - 1; m2 &= m2 - 1;
                     stg_f(&bufA[(w2 * 32 + b_) * HD + ln], 0.f); }
    }
    for (int i = tid; i < BMW; i += MTPB) {
        unsigned u1 = ldg_u(&B1[i]);
        bmA[i] = u1;
        bmB[i] = u1 | ldg_u(&B2[i]);
    }
    __syncthreads();
#pragma unroll
    for (int j = 0; j < NILP; ++j) {
        int t = gtid + j * MNTH;
        if (t >= NE4) continue;
#pragma unroll
        for (int k = 0; k < 4; ++k) {
            int d = cmp4(vd[j], k);
            if ((bmA[d >> 5] >> (d & 31)) & 1u) {
                int e = t * 4 + k, s = src[e];
                atomicOr(&EB1[e >> 5], 1u << (e & 31));
                unsigned m = 1u << (s & 31);
                unsigned old = atomicOr(&B0[s >> 5], m);
                if (!(old & m)) stg_f(&cnt_out[s], 0.f);
            }
            if (((bmB[d >> 5] >> (d & 31)) & 1u) || d == p0 || d == p1)
                atomicAdd(&cnt_in[d], 1.0f);
        }
    }
    // prefetch D's src int4s (read-only input: legal to load any time);
    // the ~900cy load chain hides under the barrier wait below.
    int4 vs[NILP];
#pragma unroll
    for (int j = 0; j < NILP; ++j) {
        int t = gtid + j * MNTH;
        vs[j] = (t < NE4) ? ((const int4*)src)[t] : make_int4(-1, -1, -1, -1);
    }
    gbar(cnt16, rel16, 3u * MBLK, 3u);

    // ---- D: out-deg sweep over union B0 (uses prefetched vs) ----
    for (int i = tid; i < BMW; i += MTPB) bmB[i] = ldg_u(&B0[i]);
    __syncthreads();
#pragma unroll
    for (int j = 0; j < NILP; ++j) {
        int t = gtid + j * MNTH;
        if (t >= NE4) continue;
#pragma unroll
        for (int k = 0; k < 4; ++k) {
            int s = cmp4(vs[j], k);
            if ((bmB[s >> 5] >> (s & 31)) & 1u) atomicAdd(&cnt_out[s], 1.0f);
        }
    }
    // prefetch E's EB1 word (EB1 final since gbar(3); D doesn't write it)
    unsigned eb1w = (ew < EBW) ? ldg_u(&EB1[ew]) : 0u;
    gbar(cnt16, rel16, 4u * MBLK, 4u);

    // ---- E: scatter1 via EB1 (lane-distributed, prefetched word) ----
    // agg1[d] += w0(s) * zt[z[s]]; edge order per wave = ascending edge id.
    {
        unsigned long long act = __ballot(eb1w != 0u);
        while (act) {
            int lb = __ffsll(act) - 1; act &= act - 1ULL;
            unsigned wd = __shfl(eb1w, lb, 64);
            int ebase = (gw * 64 + lb) * 32;
            while (wd) {
                int b_ = __ffs(wd) - 1; wd &= wd - 1;
                int e = ebase + b_;
                int s = src[e], d = dst[e];
                float w0 = 1.0f / sqrtf(fmaxf(ldg_f(&cnt_out[s]), 1.0f));
                atomicAdd(&bufB[d * HD + ln], w0 * zt[z[s] * HD + ln]);
            }
        }
    }
    // prefetch G's EB2 word (EB2 final since gbar(2))
    unsigned eb2w = (ew < EBW) ? ldg_u(&EB2[ew]) : 0u;
    gbar(cnt16, rel16, 5u * MBLK, 5u);

    // ---- F: gemm1 over B1 bits — x1 = relu((agg1*nin)@W1+b1) in bufB ----
    for (int w2 = gw; w2 < BMW; w2 += MWAVES) {
        unsigned mk = ldg_u(&B1[w2]);
        while (mk) {
            int b_ = __ffs(mk) - 1; mk &= mk - 1;
            int v = w2 * 32 + b_;
            float nin = 1.0f / sqrtf(fmaxf(ldg_f(&cnt_in[v]), 1.0f));
            arow[wv][ln] = ldg_f(&bufB[v * HD + ln]) * nin;
            float acc = b1[ln];
#pragma unroll
            for (int i = 0; i < HD; ++i)
                acc += arow[wv][i] * W1[i * HD + ln];
            stg_f(&bufB[v * HD + ln], fmaxf(acc, 0.0f));
        }
    }
    gbar(cnt16, rel16, 6u * MBLK, 6u);

    // ---- G: scatter2 via EB2 (prefetched word) — agg2[d] += w0(s)*x1[s] ----
    {
        unsigned long long act = __ballot(eb2w != 0u);
        while (act) {
            int lb = __ffsll(act) - 1; act &= act - 1ULL;
            unsigned wd = __shfl(eb2w, lb, 64);
            int ebase = (gw * 64 + lb) * 32;
            while (wd) {
                int b_ = __ffs(wd) - 1; wd &= wd - 1;
                int e = ebase + b_;
                int s = src[e], d = dst[e];
                float w0 = 1.0f / sqrtf(fmaxf(ldg_f(&cnt_out[s]), 1.0f));
                atomicAdd(&bufA[d * HD + ln], w0 * ldg_f(&bufB[s * HD + ln]));
            }
        }
    }
    gbar(cnt16, rel16, 7u * MBLK, 7u);

    // ---- H: gemm2 over B2 bits + fused scatter3 via cpair multiplicities ----
    for (int w2 = gw; w2 < BMW; w2 += MWAVES) {
        unsigned mk = ldg_u(&B2[w2]);
        while (mk) {
            int b_ = __ffs(mk) - 1; mk &= mk - 1;
            int v = w2 * 32 + b_;
            float nin = 1.0f / sqrtf(fmaxf(ldg_f(&cnt_in[v]), 1.0f));
            arow[wv][ln] = ldg_f(&bufA[v * HD + ln]) * nin;
            float acc = b2[ln];
#pragma unroll
            for (int i = 0; i < HD; ++i)
                acc += arow[wv][i] * W2[i * HD + ln];
            float x2 = fmaxf(acc, 0.0f);
            int cp = ldg_i(&cpair[v]);
            int c0 = cp & 0xffff, c1 = cp >> 16;
            float w0v = 1.0f / sqrtf(fmaxf(ldg_f(&cnt_out[v]), 1.0f));
            if (c0) atomicAdd(&x3buf[ln], (float)c0 * (w0v * x2));
            if (c1) atomicAdd(&x3buf[HD + ln], (float)c1 * (w0v * x2));
        }
    }

    // ---- barrier 8: arrive-and-exit for blocks != 0; block 0 waits ----
    __syncthreads();
    if (tid == 0)
        __hip_atomic_fetch_add(&cnt16[(blk & 15) * 16], 1u,
                               __ATOMIC_RELAXED, __HIP_MEMORY_SCOPE_AGENT);
    if (blk != 0) return;
    if (tid == 0) {
        long guard = 0;
        for (;;) {
            unsigned s = 0;
#pragma unroll
            for (int i = 0; i < 16; ++i)
                s += __hip_atomic_load(&cnt16[i * 16], __ATOMIC_RELAXED,
                                       __HIP_MEMORY_SCOPE_AGENT);
            if (s >= 8u * MBLK) break;
            __builtin_amdgcn_s_sleep(1);
            if (++guard > (1L << 22)) break;
        }
        asm volatile("" ::: "memory");
    }
    __syncthreads();

    // ---- J (block 0): gemm3 (no relu) + final MLP ----
    if (tid < 128) {
        int pv = wv ? p1 : p0;
        int rs = (wv && p1 != p0) ? 1 : 0;       // p0==p1: both use row 0
        float nin = 1.0f / sqrtf(fmaxf(ldg_f(&cnt_in[pv]), 1.0f));
        arow[wv][ln] = ldg_f(&x3buf[rs * HD + ln]) * nin;
        float acc = b3[ln];
#pragma unroll
        for (int i = 0; i < HD; ++i)
            acc += arow[wv][i] * W3[i * HD + ln];
        xls[wv * HD + ln] = acc;
    }
    __syncthreads();
    if (tid < 64) {
        arow[0][tid] = xls[tid] * xls[HD + tid];   // h
        float t2 = l1b[tid];
#pragma unroll
        for (int i = 0; i < HD; ++i)
            t2 += arow[0][i] * l1w[i * HD + tid];
        t2 = fmaxf(t2, 0.0f);
        float val = t2 * l2w[tid];
#pragma unroll
        for (int off = 32; off; off >>= 1)
            val += __shfl_down(val, off, 64);
        if (tid == 0) out[0] = val + l2b[0];
    }
}

extern "C" void kernel_launch(void* const* d_in, const int* in_sizes, int n_in,
                              void* d_out, int out_size, void* d_ws, size_t ws_size,
                              hipStream_t stream) {
    const int*   z    = (const int*)d_in[0];
    const int*   src  = (const int*)d_in[1];
    const int*   dst  = (const int*)d_in[2];
    const int*   pair = (const int*)d_in[3];
    const float* zt   = (const float*)d_in[4];
    const float* W1   = (const float*)d_in[5];
    const float* b1   = (const float*)d_in[6];
    const float* W2   = (const float*)d_in[7];
    const float* b2   = (const float*)d_in[8];
    const float* W3   = (const float*)d_in[9];
    const float* b3   = (const float*)d_in[10];
    const float* l1w  = (const float*)d_in[11];
    const float* l1b  = (const float*)d_in[12];
    const float* l2w  = (const float*)d_in[13];
    const float* l2b  = (const float*)d_in[14];
    float* out = (float*)d_out;

    char* w = (char*)d_ws;
    auto alloc = [&](size_t bytes) {
        char* p = w;
        w += (bytes + 255) & ~(size_t)255;
        return p;
    };
    // contiguous memset region: [cnt16 | rel16 | x3buf | B0 B1 B2 | EB1 EB2 | cpair]
    unsigned* cnt16   = (unsigned*)alloc(1024);
    unsigned* rel16   = (unsigned*)alloc(1024);
    float*    x3buf   = (float*)alloc(2 * HD * 4);
    unsigned* B0      = (unsigned*)alloc((size_t)BMW * 4);
    unsigned* B1      = (unsigned*)alloc((size_t)BMW * 4);
    unsigned* B2      = (unsigned*)alloc((size_t)BMW * 4);
    unsigned* EB1     = (unsigned*)alloc((size_t)EBW * 4);
    unsigned* EB2     = (unsigned*)alloc((size_t)EBW * 4);
    int*      cpair   = (int*)alloc((size_t)NN * 4);
    char*     zend    = w;
    float*    bufA    = (float*)alloc((size_t)NN * HD * 4);
    float*    bufB    = (float*)alloc((size_t)NN * HD * 4);
    float*    cnt_out = (float*)alloc((size_t)NN * 4);
    float*    cnt_in  = (float*)alloc((size_t)NN * 4);

    hipMemsetAsync(cnt16, 0, (size_t)(zend - (char*)cnt16), stream);
    k_main<<<MBLK, MTPB, 0, stream>>>(z, src, dst, pair, zt,
                                      W1, b1, W2, b2, W3, b3,
                                      l1w, l1b, l2w, l2b, out,
                                      bufA, bufB, x3buf, cnt_out, cnt_in,
                                      cpair, B0, B1, B2, EB1, EB2, cnt16, rel16);
}